// Round 10
// baseline (642.730 us; speedup 1.0000x reference)
//
#include <hip/hip_runtime.h>
#include <cstddef>
#include <cstdint>

#define TIME_N 262144
#define BATCH  32
#define KW     1024
#define ST     256
#define CUTN   513
#define TCN    1026
#define FN     1029   // frames
#define FPAD   1152
#define CPAD   1152
#define XLEN   (FPAD * ST + KW)   // 295936 bf16 per batch row
#define XBLK   (XLEN / 256)       // 1156

// mask GEMM dims
#define MROWS  (BATCH * FN)   // 32928
#define MP     33024          // 258*128
#define KPH    544            // 513 -> 17*32
#define NPH    640            // 513 -> 5*128
// convT GEMM dims / flat bf16 t layout (re/im PAIR-INTERLEAVED: col 2y=re_y, 2y+1=im_y)
#define TBP    1040           // flat bf16 t row stride (16B-aligned, 65*16)
#define FLATB  (FN * TBP)     // per-batch flat size
#define KPC    4160           // 4*1040 = 65*64

// k_prep block ranges (round-7 layout: wdb one block per k, r = tid)
#define PB_XPAD  (XBLK * BATCH)            // 36992
#define PB_WBF   (PB_XPAD + CPAD)          // +1152
#define PB_WLIN  (PB_WBF + NPH)            // +640
#define PB_TOTAL (PB_WLIN + KPC)           // +4160

typedef __bf16 bf16x8 __attribute__((ext_vector_type(8)));
typedef float floatx4 __attribute__((ext_vector_type(4)));
typedef int   intx4   __attribute__((ext_vector_type(4)));

__device__ __forceinline__ unsigned short f2bf(float f) {
    union { float f; unsigned u; } v; v.f = f;
    unsigned r = (v.u + 0x7fffu + ((v.u >> 16) & 1u)) >> 16;
    return (unsigned short)r;
}
__device__ __forceinline__ float bf2f(unsigned short s) {
    union { unsigned u; float f; } v; v.u = ((unsigned)s) << 16;
    return v.f;
}
// interleaved column n -> original channel index
__device__ __forceinline__ int permch(int n) {
    return (n & 1) ? (CUTN + (n >> 1)) : (n >> 1);
}

__device__ __forceinline__ void load_lds16(const void* g, void* l) {
    __builtin_amdgcn_global_load_lds(
        (const __attribute__((address_space(1))) void*)g,
        (__attribute__((address_space(3))) void*)l, 16, 0, 0);
}

// ---------------------------------------------------------------------------
// k_prep: all input-conversion work in ONE launch, split by blockIdx range.
// (round-7 version — the r8 wdb transpose + maskm rewrite cost +30us net)
// ---------------------------------------------------------------------------
__global__ __launch_bounds__(256) void k_prep(
    const float* __restrict__ x, const float* __restrict__ c1w,
    const float* __restrict__ lw, const float* __restrict__ wct,
    unsigned short* __restrict__ xb, unsigned short* __restrict__ wbf,
    unsigned short* __restrict__ wlb, unsigned short* __restrict__ wdb)
{
    const int bid = blockIdx.x;
    if (bid < PB_XPAD) {
        const int b = bid / XBLK;
        const int p = (bid - b * XBLK) * 256 + threadIdx.x;
        const int g = p - KW;
        float v = (g >= 0 && g < TIME_N) ? x[(size_t)b * TIME_N + g] : 0.0f;
        xb[(size_t)b * XLEN + p] = f2bf(v);
    } else if (bid < PB_WBF) {
        const int n = bid - PB_XPAD;              // 0..1151 interleaved row
        const int ch = (n < TCN) ? permch(n) : 0;
        for (int k = threadIdx.x; k < KW; k += 256) {
            float v = (n < TCN) ? c1w[(size_t)ch * KW + k] : 0.0f;
            wbf[(size_t)n * KW + k] = f2bf(v);
        }
    } else if (bid < PB_WLIN) {
        const int n = bid - PB_WBF;               // 0..639
        for (int k = threadIdx.x; k < KPH; k += 256) {
            float v = (n < CUTN && k < CUTN) ? lw[(size_t)n * CUTN + k] : 0.0f;
            wlb[(size_t)n * KPH + k] = f2bf(v);
        }
    } else {
        const int k = bid - PB_WLIN;              // 0..4159
        const int r = threadIdx.x;                // 0..255
        const int j = k / TBP;
        const int n = k - j * TBP;
        float v = 0.0f;
        if (n < TCN) {
            const int ch = permch(n);
            const int widx = (3 - j) * 256 + r;
            v = wct[(size_t)(2 * ch) * KW + widx] -
                wct[(size_t)(2 * ch + 1) * KW + widx];
        }
        wdb[(size_t)r * KPC + k] = f2bf(v);
    }
}

// ---------------------------------------------------------------------------
// k_conv1m (MFMA): conv1 bf16 GEMM, 128x128 tile — ZERO-LDS, ZERO-BARRIER
// K-loop. All seven prior schedule levers (swizzle/BK/dbuf/counted-vmcnt/
// occupancy/2-deep) were null because every variant kept the
// stage->LDS->barrier->read->barrier convoy; per-CU accounting shows the LDS
// pipe (~600cy/K-step) dominates the MFMA pipe (~310cy). Here MFMA fragments
// load DIRECTLY global->VGPR (lane(lm,lq) reads 16B at A[row+lm][lq*8], both
// operands contiguous in k; 16x64B segments/inst = fully 64B-efficient).
// Cost: 2x L2 reads (each panel read by 2 waves) — L2 has 4x headroom.
// Register ping-pong (2 K-steps/iter, static indexing) overlaps loads of
// step t+1 under MFMAs of step t; waves run barrier-free (m114 overlap).
// Final preload overreads <=64B past wbf (into wdb, same d_ws) — unused.
// Epilogue: r9's LDS-staged + XOR-swizzled (WRITE ideal, conflicts 0).
// ---------------------------------------------------------------------------
__global__ __launch_bounds__(256) void k_conv1m(
    const unsigned short* __restrict__ xb, const unsigned short* __restrict__ wb,
    const float* __restrict__ gamma,
    const float* __restrict__ c1w, const float* __restrict__ c1b,
    const float* __restrict__ c2w, const float* __restrict__ c2b,
    unsigned short* __restrict__ tb2, unsigned short* __restrict__ h)
{
    extern __shared__ __align__(16) char lds[];   // 48KB epilogue stage only

    const int flat = blockIdx.x;
    const int xcd = flat & 7;
    const int idx = flat >> 3;              // 0..323
    const int cb  = idx % 9;
    const int pr  = xcd * 36 + idx / 9;     // 0..287 (b,fb) pair
    const int b   = pr / 9;
    const int fb  = pr % 9;
    const int f0 = fb * 128, c0 = cb * 128;
    const int tid = threadIdx.x;

    const int wave = tid >> 6, lane = tid & 63;
    const int lm = lane & 15, lq = lane >> 4;
    const int mw = (wave & 1) * 64, nw = (wave >> 1) * 64;

    // per-lane direct fragment pointers
    const unsigned short* xrow = xb + (size_t)b * XLEN;
    const unsigned short* pa[4];
    const unsigned short* pb[4];
#pragma unroll
    for (int mt = 0; mt < 4; ++mt)
        pa[mt] = xrow + (size_t)(f0 + mw + mt * 16 + lm) * ST + lq * 8;
#pragma unroll
    for (int nt = 0; nt < 4; ++nt)
        pb[nt] = wb + (size_t)(c0 + nw + nt * 16 + lm) * KW + lq * 8;

    floatx4 acc[4][4];
#pragma unroll
    for (int i = 0; i < 4; ++i)
#pragma unroll
        for (int j = 0; j < 4; ++j) acc[i][j] = (floatx4)0.0f;

    bf16x8 aA[4], bA[4], aB[4], bB[4];
    // preload K-step 0
#pragma unroll
    for (int mt = 0; mt < 4; ++mt) { aA[mt] = *(const bf16x8*)pa[mt]; pa[mt] += 32; }
#pragma unroll
    for (int nt = 0; nt < 4; ++nt) { bA[nt] = *(const bf16x8*)pb[nt]; pb[nt] += 32; }

    for (int t = 0; t < 16; ++t) {           // 2 K-steps per iteration
        // load K-step 2t+1
#pragma unroll
        for (int mt = 0; mt < 4; ++mt) { aB[mt] = *(const bf16x8*)pa[mt]; pa[mt] += 32; }
#pragma unroll
        for (int nt = 0; nt < 4; ++nt) { bB[nt] = *(const bf16x8*)pb[nt]; pb[nt] += 32; }
        // MFMA K-step 2t
#pragma unroll
        for (int mt = 0; mt < 4; ++mt)
#pragma unroll
            for (int nt = 0; nt < 4; ++nt)
                acc[mt][nt] = __builtin_amdgcn_mfma_f32_16x16x32_bf16(
                    aA[mt], bA[nt], acc[mt][nt], 0, 0, 0);
        // load K-step 2t+2 (t=15: dead overread, stays in d_ws)
#pragma unroll
        for (int mt = 0; mt < 4; ++mt) { aA[mt] = *(const bf16x8*)pa[mt]; pa[mt] += 32; }
#pragma unroll
        for (int nt = 0; nt < 4; ++nt) { bA[nt] = *(const bf16x8*)pb[nt]; pb[nt] += 32; }
        // MFMA K-step 2t+1
#pragma unroll
        for (int mt = 0; mt < 4; ++mt)
#pragma unroll
            for (int nt = 0; nt < 4; ++nt)
                acc[mt][nt] = __builtin_amdgcn_mfma_f32_16x16x32_bf16(
                    aB[mt], bB[nt], acc[mt][nt], 0, 0, 0);
    }

    // ---- epilogue phase E1: compute + stage into LDS (XOR-swizzled) ----
    float w1[16], b1[8], w2[8];
#pragma unroll
    for (int o = 0; o < 8; ++o) {
        w1[2 * o]     = c1w[2 * o];
        w1[2 * o + 1] = c1w[2 * o + 1];
        b1[o] = c1b[o];
        w2[o] = c2w[o];
    }
    const float b2v = c2b[0];
    const bool evenlane = ((lane & 1) == 0);

#pragma unroll
    for (int nt = 0; nt < 4; ++nt) {
        const int nl = nw + nt * 16 + lm;        // local col 0..127
        const int n = c0 + nl;
        const bool valid_c = (n < TCN);
        const float gv = valid_c ? gamma[permch(n)] : 0.0f;
        const int nbl = nl & ~1;                 // local pair col
        const int yl  = nl >> 1;                 // local ybase 0..63
#pragma unroll
        for (int mt = 0; mt < 4; ++mt) {
#pragma unroll
            for (int rp = 0; rp < 2; ++rp) {
                const int ra = rp * 2;
                const int fl = mw + mt * 16 + lq * 4 + ra;   // local frame
                const float ua = acc[mt][nt][ra] * gv;
                const float ub = acc[mt][nt][ra + 1] * gv;
                const float ta  = 2.0f / (1.0f + __expf(-2.0f * ua)) - 1.0f;
                const float tbv = 2.0f / (1.0f + __expf(-2.0f * ub)) - 1.0f;
                const float sa = __shfl_xor(ta, 1);
                const float sb = __shfl_xor(tbv, 1);
                const int  fme = evenlane ? fl : (fl + 1);
                const float re = evenlane ? ta : sb;
                const float im = evenlane ? sa : tbv;
                const unsigned pr2 = (unsigned)f2bf(re) |
                                     ((unsigned)f2bf(im) << 16);
                const int xr = ((fme & 1) << 5) | (((fme >> 2) & 1) << 6);
                *(unsigned*)(lds + fme * 256 + ((nbl * 2) ^ xr)) = pr2;
                float a2 = b2v;
#pragma unroll
                for (int o = 0; o < 8; ++o) {
                    const float a1 = fmaxf(
                        re * w1[2 * o] + im * w1[2 * o + 1] + b1[o], 0.0f);
                    a2 += a1 * w2[o];
                }
                const int xh = ((fme & 1) << 4) | (((fme >> 2) & 1) << 5);
                *(unsigned short*)(lds + 32768 + fme * 128 + ((yl * 2) ^ xh)) =
                    f2bf(fmaxf(a2, 0.0f));
            }
        }
    }
    __syncthreads();

    // ---- epilogue phase E2: coalesced copy-out (full-line stores) ----
    const int vch = min(16, max(0, (520 - (c0 >> 1)) >> 2));   // 16B = 4 pairs
    unsigned short* tbb = tb2 + (size_t)b * FLATB;
#pragma unroll
    for (int i = 0; i < 8; ++i) {
        const int c = i * 256 + tid;             // chunk 0..2047
        const int fl = c >> 4;                   // row 0..127
        const int c16 = c & 15;                  // chunk in row
        if (f0 + fl < FN && c16 < vch) {
            const int xr = ((fl & 1) << 5) | (((fl >> 2) & 1) << 6);
            const intx4 v = *(const intx4*)(lds + fl * 256 + ((c16 * 16) ^ xr));
            *(intx4*)(tbb + (size_t)(f0 + fl) * TBP + (c0 + c16 * 8)) = v;
        }
    }
    const int vhc = min(8, max(0, (544 - (c0 >> 1)) >> 3));    // 16B = 8 shorts
#pragma unroll
    for (int i = 0; i < 4; ++i) {
        const int c = i * 256 + tid;             // chunk 0..1023
        const int fl = c >> 3;                   // row 0..127
        const int c16 = c & 7;
        if (f0 + fl < FN && c16 < vhc) {
            const int xh = ((fl & 1) << 4) | (((fl >> 2) & 1) << 5);
            const intx4 v = *(const intx4*)(lds + 32768 + fl * 128 +
                                            ((c16 * 16) ^ xh));
            *(intx4*)(h + ((size_t)b * FN + f0 + fl) * KPH +
                      ((c0 >> 1) + c16 * 8)) = v;
        }
    }
}

// ---------------------------------------------------------------------------
// k_maskm (MFMA): hh = H * Wlin^T; mask = sigmoid(2*(hh+b)*g);
// RMW: one aligned uint per (m,y) scales the (re,im) pair in tb2.
// (round-7 version)
// ---------------------------------------------------------------------------
__global__ __launch_bounds__(256) void k_maskm(
    const unsigned short* __restrict__ h, const unsigned short* __restrict__ wlb,
    const float* __restrict__ linb, const float* __restrict__ fcg,
    unsigned* __restrict__ tbu)
{
    __shared__ __align__(16) unsigned short As[128 * 32];
    __shared__ __align__(16) unsigned short Bs[128 * 32];

    const int m0 = blockIdx.x * 128, n0 = blockIdx.y * 128;
    const int tid = threadIdx.x;

    const int s0 = tid, s1 = tid + 256;
    const int ar0 = s0 >> 2, aq0 = s0 & 3;
    const int ar1 = s1 >> 2, aq1 = s1 & 3;
    const unsigned short* ga0 = h + (size_t)(m0 + ar0) * KPH + aq0 * 8;
    const unsigned short* ga1 = h + (size_t)(m0 + ar1) * KPH + aq1 * 8;
    const unsigned short* gb0 = wlb + (size_t)(n0 + ar0) * KPH + aq0 * 8;
    const unsigned short* gb1 = wlb + (size_t)(n0 + ar1) * KPH + aq1 * 8;
    unsigned short* la0 = &As[s0 * 8];
    unsigned short* la1 = &As[s1 * 8];
    unsigned short* lb0 = &Bs[s0 * 8];
    unsigned short* lb1 = &Bs[s1 * 8];

    const int wave = tid >> 6, lane = tid & 63;
    const int lm = lane & 15, lq = lane >> 4;
    const int mw = (wave & 1) * 64, nw = (wave >> 1) * 64;
    const unsigned short* Ap = &As[(mw + lm) * 32 + lq * 8];
    const unsigned short* Bp = &Bs[(nw + lm) * 32 + lq * 8];

    floatx4 acc[4][4];
#pragma unroll
    for (int i = 0; i < 4; ++i)
#pragma unroll
        for (int j = 0; j < 4; ++j) acc[i][j] = (floatx4)0.0f;

    for (int ks = 0; ks < KPH / 32; ++ks) {
        load_lds16(ga0, la0);
        load_lds16(ga1, la1);
        load_lds16(gb0, lb0);
        load_lds16(gb1, lb1);
        ga0 += 32; ga1 += 32; gb0 += 32; gb1 += 32;
        __syncthreads();

        bf16x8 afr[4], bfr[4];
#pragma unroll
        for (int mt = 0; mt < 4; ++mt) afr[mt] = *(const bf16x8*)(Ap + mt * 16 * 32);
#pragma unroll
        for (int nt = 0; nt < 4; ++nt) bfr[nt] = *(const bf16x8*)(Bp + nt * 16 * 32);
#pragma unroll
        for (int mt = 0; mt < 4; ++mt)
#pragma unroll
            for (int nt = 0; nt < 4; ++nt)
                acc[mt][nt] = __builtin_amdgcn_mfma_f32_16x16x32_bf16(
                    afr[mt], bfr[nt], acc[mt][nt], 0, 0, 0);
        __syncthreads();
    }

#pragma unroll
    for (int nt = 0; nt < 4; ++nt) {
        const int y = n0 + nw + nt * 16 + lm;
        if (y < CUTN) {
            const float lb = linb[y];
            const float gv = fcg[y];
#pragma unroll
            for (int mt = 0; mt < 4; ++mt) {
#pragma unroll
                for (int r = 0; r < 4; ++r) {
                    const int m = m0 + mw + mt * 16 + lq * 4 + r;
                    if (m < MROWS) {
                        const float v = (acc[mt][nt][r] + lb) * gv;
                        const float msk = 1.0f / (1.0f + __expf(-2.0f * v));
                        unsigned* p = tbu + (size_t)m * (TBP / 2) + y;
                        const unsigned u = *p;
                        const float re = bf2f((unsigned short)(u & 0xffffu)) * msk;
                        const float im = bf2f((unsigned short)(u >> 16)) * msk;
                        *p = (unsigned)f2bf(re) | ((unsigned)f2bf(im) << 16);
                    }
                }
            }
        }
    }
}

// ---------------------------------------------------------------------------
// k_convtm (MFMA): d[m][r] = A(tb2 windows) * Wd^T, fused sigmoid softmax.
// (round-7 version: 128x128, BK=64, T3-minimum dbuf, LDS-staged out)
// ---------------------------------------------------------------------------
__global__ __launch_bounds__(256) void k_convtm(
    const unsigned short* __restrict__ tb2, const unsigned short* __restrict__ wdb,
    float* __restrict__ out)
{
    extern __shared__ __align__(16) char lds[];   // 64KB (2x32KB dbuf; reused as stage)

    const int m0 = blockIdx.x * 128, n0 = blockIdx.y * 128;
    const int b   = m0 >> 10;
    const int ml0 = m0 & 1023;
    const int tid = threadIdx.x;

    const unsigned short* tbb = tb2 + (size_t)b * FLATB;
    const unsigned short* ga[4];
    const unsigned short* gb[4];
    int qa[4];
#pragma unroll
    for (int i = 0; i < 4; ++i) {
        const int c = i * 256 + tid;             // chunk 0..1023
        const int row = c >> 3;                  // 0..127
        const int colb = (c & 7) * 16;
        const int es = (colb ^ ((row & 7) << 4)) >> 1;
        qa[i] = c * 16;
        ga[i] = tbb + (size_t)(ml0 + row + 1) * TBP + es;
        gb[i] = wdb + (size_t)(n0 + row) * KPC + es;
    }

    const int wave = tid >> 6, lane = tid & 63;
    const int lm = lane & 15, lq = lane >> 4;
    const int mw = (wave & 1) * 64, nw = (wave >> 1) * 64;
    const int swz = (lm & 7) << 4;
    int abo[2], bbo[2];
#pragma unroll
    for (int ks = 0; ks < 2; ++ks) {
        abo[ks] = (mw + lm) * 128 + ((ks * 64 + lq * 16) ^ swz);
        bbo[ks] = 16384 + (nw + lm) * 128 + ((ks * 64 + lq * 16) ^ swz);
    }

    floatx4 acc[4][4];
#pragma unroll
    for (int i = 0; i < 4; ++i)
#pragma unroll
        for (int j = 0; j < 4; ++j) acc[i][j] = (floatx4)0.0f;

    // prologue: stage K-tile 0 into buf 0
#pragma unroll
    for (int i = 0; i < 4; ++i) {
        load_lds16(ga[i], lds + qa[i]);
        load_lds16(gb[i], lds + 16384 + qa[i]);
        ga[i] += 64; gb[i] += 64;
    }
    __syncthreads();

    for (int t = 0; t < KPC / 64; ++t) {
        char* cur = lds + (t & 1) * 32768;
        char* nxt = lds + ((t + 1) & 1) * 32768;

        if (t + 1 < KPC / 64) {
#pragma unroll
            for (int i = 0; i < 4; ++i) {
                load_lds16(ga[i], nxt + qa[i]);
                load_lds16(gb[i], nxt + 16384 + qa[i]);
                ga[i] += 64; gb[i] += 64;
            }
        }

        bf16x8 afr[4][2], bfr[4][2];
#pragma unroll
        for (int mt = 0; mt < 4; ++mt)
#pragma unroll
            for (int ks = 0; ks < 2; ++ks)
                afr[mt][ks] = *(const bf16x8*)(cur + abo[ks] + mt * 2048);
#pragma unroll
        for (int nt = 0; nt < 4; ++nt)
#pragma unroll
            for (int ks = 0; ks < 2; ++ks)
                bfr[nt][ks] = *(const bf16x8*)(cur + bbo[ks] + nt * 2048);
#pragma unroll
        for (int mt = 0; mt < 4; ++mt)
#pragma unroll
            for (int nt = 0; nt < 4; ++nt)
#pragma unroll
                for (int ks = 0; ks < 2; ++ks)
                    acc[mt][nt] = __builtin_amdgcn_mfma_f32_16x16x32_bf16(
                        afr[mt][ks], bfr[nt][ks], acc[mt][nt], 0, 0, 0);
        __syncthreads();
    }

    // ---- E1: stage p0 block into LDS: [ml 0..127][nl 0..127] f32 (64KB) ----
#pragma unroll
    for (int nt = 0; nt < 4; ++nt) {
        const int nl = nw + nt * 16 + lm;
#pragma unroll
        for (int mt = 0; mt < 4; ++mt) {
#pragma unroll
            for (int r = 0; r < 4; ++r) {
                const int ml = mw + mt * 16 + lq * 4 + r;
                const float d = acc[mt][nt][r];
                const float p0 = 1.0f / (1.0f + __expf(-d));
                *(float*)(lds + ml * 512 + nl * 4) = p0;
            }
        }
    }
    __syncthreads();

    // ---- E2: coalesced copy-out (full 128B lines), p and 1-p ----
    float* ob = out + (size_t)b * 2 * TIME_N;
#pragma unroll
    for (int i = 0; i < 16; ++i) {
        const int c = i * 256 + tid;             // chunk 0..4095 (16B)
        const int ml = c >> 5;                   // row 0..127
        const int c16 = c & 31;                  // chunk in row
        const floatx4 v = *(const floatx4*)(lds + c * 16);
        floatx4 w;
        w[0] = 1.0f - v[0]; w[1] = 1.0f - v[1];
        w[2] = 1.0f - v[2]; w[3] = 1.0f - v[3];
        const int tau = (ml0 + ml) * 256 + n0 + c16 * 4;
        *(floatx4*)(ob + tau)          = v;
        *(floatx4*)(ob + TIME_N + tau) = w;
    }
}

extern "C" void kernel_launch(void* const* d_in, const int* in_sizes, int n_in,
                              void* d_out, int out_size, void* d_ws, size_t ws_size,
                              hipStream_t stream)
{
    const float* x    = (const float*)d_in[0];
    const float* c1w  = (const float*)d_in[1];
    const float* ing  = (const float*)d_in[2];
    const float* cb1w = (const float*)d_in[3];
    const float* cb1b = (const float*)d_in[4];
    const float* cb2w = (const float*)d_in[5];
    const float* cb2b = (const float*)d_in[6];
    const float* linw = (const float*)d_in[7];
    const float* linb = (const float*)d_in[8];
    const float* fcg  = (const float*)d_in[9];
    const float* ctw  = (const float*)d_in[10];
    float* out = (float*)d_out;

    // ---- workspace layout (all bf16) ----
    unsigned short* tb2 = (unsigned short*)d_ws;           // 32*1029*1040
    unsigned short* h   = tb2 + (size_t)BATCH * FLATB;     // 33024*544
    unsigned short* wlb = h + (size_t)MP * KPH;            // 640*544
    unsigned short* xb  = wlb + (size_t)NPH * KPH;         // 32*XLEN
    unsigned short* wbf = xb + (size_t)BATCH * XLEN;       // 1152*1024
    unsigned short* wdb = wbf + (size_t)CPAD * KW;         // 256*4160

    hipLaunchKernelGGL(k_prep, dim3(PB_TOTAL), dim3(256), 0, stream,
                       x, c1w, linw, ctw, xb, wbf, wlb, wdb);
    hipLaunchKernelGGL(k_conv1m, dim3(BATCH * 9 * 9), dim3(256), 49152, stream,
                       xb, wbf, ing, cb1w, cb1b, cb2w, cb2b, tb2, h);
    hipLaunchKernelGGL(k_maskm, dim3(MP / 128, NPH / 128), dim3(256), 0, stream,
                       h, wlb, linb, fcg, (unsigned*)tb2);
    hipLaunchKernelGGL(k_convtm, dim3(256, 2), dim3(256), 65536, stream,
                       tb2, wdb, out);
}

// Round 11
// 439.197 us; speedup vs baseline: 1.4634x; 1.4634x over previous
//
#include <hip/hip_runtime.h>
#include <cstddef>
#include <cstdint>

#define TIME_N 262144
#define BATCH  32
#define KW     1024
#define ST     256
#define CUTN   513
#define TCN    1026
#define FN     1029   // frames
#define FPAD   1152
#define CPAD   1152
#define XLEN   (FPAD * ST + KW)   // 295936 bf16 per batch row
#define XBLK   (XLEN / 256)       // 1156

// mask GEMM dims
#define MROWS  (BATCH * FN)   // 32928
#define MP     33024          // 258*128
#define KPH    544            // 513 -> 17*32
#define NPH    640            // 513 -> 5*128
// convT GEMM dims / flat bf16 t layout (re/im PAIR-INTERLEAVED: col 2y=re_y, 2y+1=im_y)
#define TBP    1040           // flat bf16 t row stride (16B-aligned, 65*16)
#define FLATB  (FN * TBP)     // per-batch flat size
#define KPC    4160           // 4*1040 = 65*64

// k_prep block ranges
#define PB_XPAD  (XBLK * BATCH)            // 36992
#define PB_WBF   (PB_XPAD + CPAD)          // +1152
#define PB_WLIN  (PB_WBF + NPH)            // +640
#define PB_TOTAL (PB_WLIN + KPC)           // +4160

// conv1m 256x128 phased-pipeline geometry
#define C1_MT   129                        // ceil(32928/256) M-tiles
#define C1_NWG  (C1_MT * 9)                // 1161 blocks
#define C1_BUF  49152                      // A 32KB + B 16KB per K-tile
#define C1_LDS  (3 * C1_BUF)               // 147456 ring; epilogue reuses 96KB

typedef __bf16 bf16x8 __attribute__((ext_vector_type(8)));
typedef float floatx4 __attribute__((ext_vector_type(4)));
typedef int   intx4   __attribute__((ext_vector_type(4)));

__device__ __forceinline__ unsigned short f2bf(float f) {
    union { float f; unsigned u; } v; v.f = f;
    unsigned r = (v.u + 0x7fffu + ((v.u >> 16) & 1u)) >> 16;
    return (unsigned short)r;
}
__device__ __forceinline__ float bf2f(unsigned short s) {
    union { unsigned u; float f; } v; v.u = ((unsigned)s) << 16;
    return v.f;
}
// interleaved column n -> original channel index
__device__ __forceinline__ int permch(int n) {
    return (n & 1) ? (CUTN + (n >> 1)) : (n >> 1);
}

__device__ __forceinline__ void load_lds16(const void* g, void* l) {
    __builtin_amdgcn_global_load_lds(
        (const __attribute__((address_space(1))) void*)g,
        (__attribute__((address_space(3))) void*)l, 16, 0, 0);
}

// ---------------------------------------------------------------------------
// k_prep: all input-conversion work in ONE launch, split by blockIdx range.
// ---------------------------------------------------------------------------
__global__ __launch_bounds__(256) void k_prep(
    const float* __restrict__ x, const float* __restrict__ c1w,
    const float* __restrict__ lw, const float* __restrict__ wct,
    unsigned short* __restrict__ xb, unsigned short* __restrict__ wbf,
    unsigned short* __restrict__ wlb, unsigned short* __restrict__ wdb)
{
    const int bid = blockIdx.x;
    if (bid < PB_XPAD) {
        const int b = bid / XBLK;
        const int p = (bid - b * XBLK) * 256 + threadIdx.x;
        const int g = p - KW;
        float v = (g >= 0 && g < TIME_N) ? x[(size_t)b * TIME_N + g] : 0.0f;
        xb[(size_t)b * XLEN + p] = f2bf(v);
    } else if (bid < PB_WBF) {
        const int n = bid - PB_XPAD;              // 0..1151 interleaved row
        const int ch = (n < TCN) ? permch(n) : 0;
        for (int k = threadIdx.x; k < KW; k += 256) {
            float v = (n < TCN) ? c1w[(size_t)ch * KW + k] : 0.0f;
            wbf[(size_t)n * KW + k] = f2bf(v);
        }
    } else if (bid < PB_WLIN) {
        const int n = bid - PB_WBF;               // 0..639
        for (int k = threadIdx.x; k < KPH; k += 256) {
            float v = (n < CUTN && k < CUTN) ? lw[(size_t)n * CUTN + k] : 0.0f;
            wlb[(size_t)n * KPH + k] = f2bf(v);
        }
    } else {
        const int k = bid - PB_WLIN;              // 0..4159
        const int r = threadIdx.x;                // 0..255
        const int j = k / TBP;
        const int n = k - j * TBP;
        float v = 0.0f;
        if (n < TCN) {
            const int ch = permch(n);
            const int widx = (3 - j) * 256 + r;
            v = wct[(size_t)(2 * ch) * KW + widx] -
                wct[(size_t)(2 * ch + 1) * KW + widx];
        }
        wdb[(size_t)r * KPC + k] = f2bf(v);
    }
}

// ---------------------------------------------------------------------------
// k_conv1m (MFMA): conv1 bf16 GEMM — FAITHFUL phased pipeline (m196/m218
// template, adapted): 256x128 tile, BK=64, 8 waves (4Mx2N, per-wave 64x64),
// 3x48KB LDS ring. Per K-tile: 2 phases, each {issue 3 staging chunks for
// tile t+2, 8 ds_read_b128, s_barrier, lgkmcnt(0), setprio(1), 16 MFMA,
// setprio(0), s_barrier}. vmcnt(6) ONCE per tile at the boundary (tile t+2
// issued during t -> 4-phase gap covers load latency; never drained to 0 in
// the main loop). This is the structure r1 got wrong (all-at-once staging +
// boundary drain) and r4-r9's 2-barrier loop lacked (no phase interleave).
// M flattened over batch*frames (129 tiles, 1.3% pad); N = 9x128 exact.
// Bijective XCD swizzle (m204; 1161%8!=0). r9-verified LDS swizzles +
// staged epilogue (WRITE ideal, conflicts 0) extended to 256 rows.
// ---------------------------------------------------------------------------
__global__ __launch_bounds__(512) void k_conv1m(
    const unsigned short* __restrict__ xb, const unsigned short* __restrict__ wb,
    const float* __restrict__ gamma,
    const float* __restrict__ c1w, const float* __restrict__ c1b,
    const float* __restrict__ c2w, const float* __restrict__ c2b,
    unsigned short* __restrict__ tb2, unsigned short* __restrict__ h)
{
    extern __shared__ __align__(16) char lds[];   // 147456

    // bijective XCD-chunked swizzle (m204): cb fastest within a chunk
    const int orig = blockIdx.x;
    const int q = C1_NWG >> 3, r8 = C1_NWG & 7;   // 145, 1
    const int xcd = orig & 7;
    const int sid = (xcd < r8 ? xcd * (q + 1) : r8 * (q + 1) + (xcd - r8) * q)
                    + (orig >> 3);
    const int mt_i = sid / 9;
    const int cb   = sid - mt_i * 9;
    const int m0 = mt_i * 256;
    const int c0 = cb * 128;
    const int tid = threadIdx.x;

    const int wv = tid >> 6, lane = tid & 63;
    const int lm = lane & 15, lq = lane >> 4;
    const int wr = wv >> 1, wc = wv & 1;          // 4M x 2N wave grid

    // ---- staging: 3072 chunks of 16B (A 2048 + B 1024); 6 chunks/thread ----
    const unsigned short* gsrc[6];
    int ldst[6];
#pragma unroll
    for (int i = 0; i < 6; ++i) {
        const int c = i * 512 + tid;              // 0..3071
        if (c < 2048) {                           // A: [256 rows][128B]
            const int row = c >> 3;
            const int colb = (c & 7) * 16;
            const int es = (colb ^ ((row & 7) << 4)) >> 1;   // inv-swz element
            int m = m0 + row;
            if (m >= MROWS) m = MROWS - 1;        // clamp; epilogue guards
            const int b = m / FN, f = m - b * FN;
            gsrc[i] = xb + (size_t)b * XLEN + (size_t)f * ST + es;
            ldst[i] = c * 16;
        } else {                                  // B: [128 rows][128B]
            const int cc = c - 2048;
            const int row = cc >> 3;
            const int colb = (cc & 7) * 16;
            const int es = (colb ^ ((row & 7) << 4)) >> 1;
            gsrc[i] = wb + (size_t)(c0 + row) * KW + es;
            ldst[i] = 32768 + cc * 16;
        }
    }

    // ---- fragment read offsets ----
    const int swzr = (lm & 7) << 4;
    int abo[2], bbo[2];
#pragma unroll
    for (int ks = 0; ks < 2; ++ks) {
        abo[ks] = (wr * 64 + lm) * 128 + ((ks * 64 + lq * 16) ^ swzr);
        bbo[ks] = 32768 + (wc * 64 + lm) * 128 + ((ks * 64 + lq * 16) ^ swzr);
    }

    floatx4 acc[4][4];
#pragma unroll
    for (int i = 0; i < 4; ++i)
#pragma unroll
        for (int j = 0; j < 4; ++j) acc[i][j] = (floatx4)0.0f;

    // prologue: issue K-tiles 0 and 1 (12 loads in flight)
#pragma unroll
    for (int i = 0; i < 6; ++i) { load_lds16(gsrc[i], lds + ldst[i]); gsrc[i] += 64; }
#pragma unroll
    for (int i = 0; i < 6; ++i) { load_lds16(gsrc[i], lds + C1_BUF + ldst[i]); gsrc[i] += 64; }

    for (int t = 0; t < 15; ++t) {
        char* cur = lds + (t % 3) * C1_BUF;
        char* nx2 = lds + ((t + 2) % 3) * C1_BUF;
        // tile boundary: retire tile t's 6 loads (t+1's 6 stay in flight)
        asm volatile("s_waitcnt vmcnt(6)" ::: "memory");
        __builtin_amdgcn_sched_barrier(0);
        __builtin_amdgcn_s_barrier();

        // ===== phase A (ks=0): issue 3 chunks of t+2, read frags, MFMA =====
        if (t + 2 < 16) {
#pragma unroll
            for (int i = 0; i < 3; ++i) { load_lds16(gsrc[i], nx2 + ldst[i]); gsrc[i] += 64; }
        }
        bf16x8 afr[4], bfr[4];
#pragma unroll
        for (int mt = 0; mt < 4; ++mt)
            afr[mt] = *(const bf16x8*)(cur + abo[0] + mt * 2048);
#pragma unroll
        for (int nt = 0; nt < 4; ++nt)
            bfr[nt] = *(const bf16x8*)(cur + bbo[0] + nt * 2048);
        __builtin_amdgcn_s_barrier();
        asm volatile("s_waitcnt lgkmcnt(0)" ::: "memory");
        __builtin_amdgcn_sched_barrier(0);
        __builtin_amdgcn_s_setprio(1);
#pragma unroll
        for (int mt = 0; mt < 4; ++mt)
#pragma unroll
            for (int nt = 0; nt < 4; ++nt)
                acc[mt][nt] = __builtin_amdgcn_mfma_f32_16x16x32_bf16(
                    afr[mt], bfr[nt], acc[mt][nt], 0, 0, 0);
        __builtin_amdgcn_s_setprio(0);
        __builtin_amdgcn_s_barrier();

        // ===== phase B (ks=1): issue remaining 3 chunks, read frags, MFMA =====
        if (t + 2 < 16) {
#pragma unroll
            for (int i = 3; i < 6; ++i) { load_lds16(gsrc[i], nx2 + ldst[i]); gsrc[i] += 64; }
        }
#pragma unroll
        for (int mt = 0; mt < 4; ++mt)
            afr[mt] = *(const bf16x8*)(cur + abo[1] + mt * 2048);
#pragma unroll
        for (int nt = 0; nt < 4; ++nt)
            bfr[nt] = *(const bf16x8*)(cur + bbo[1] + nt * 2048);
        __builtin_amdgcn_s_barrier();
        asm volatile("s_waitcnt lgkmcnt(0)" ::: "memory");
        __builtin_amdgcn_sched_barrier(0);
        __builtin_amdgcn_s_setprio(1);
#pragma unroll
        for (int mt = 0; mt < 4; ++mt)
#pragma unroll
            for (int nt = 0; nt < 4; ++nt)
                acc[mt][nt] = __builtin_amdgcn_mfma_f32_16x16x32_bf16(
                    afr[mt], bfr[nt], acc[mt][nt], 0, 0, 0);
        __builtin_amdgcn_s_setprio(0);
        __builtin_amdgcn_s_barrier();
        // phase-B end barrier doubles as the next tile-top sync point
    }
    // ===== peeled t = 15: drain all, both phases, no issues =====
    {
        char* cur = lds + (15 % 3) * C1_BUF;
        asm volatile("s_waitcnt vmcnt(0)" ::: "memory");
        __builtin_amdgcn_sched_barrier(0);
        __builtin_amdgcn_s_barrier();

        bf16x8 afr[4], bfr[4];
#pragma unroll
        for (int ks = 0; ks < 2; ++ks) {
#pragma unroll
            for (int mt = 0; mt < 4; ++mt)
                afr[mt] = *(const bf16x8*)(cur + abo[ks] + mt * 2048);
#pragma unroll
            for (int nt = 0; nt < 4; ++nt)
                bfr[nt] = *(const bf16x8*)(cur + bbo[ks] + nt * 2048);
            asm volatile("s_waitcnt lgkmcnt(0)" ::: "memory");
            __builtin_amdgcn_sched_barrier(0);
#pragma unroll
            for (int mt = 0; mt < 4; ++mt)
#pragma unroll
                for (int nt = 0; nt < 4; ++nt)
                    acc[mt][nt] = __builtin_amdgcn_mfma_f32_16x16x32_bf16(
                        afr[mt], bfr[nt], acc[mt][nt], 0, 0, 0);
        }
    }
    __syncthreads();          // K-loop done -> LDS reusable for epilogue

    // ---- epilogue E1: compute + stage (XOR-swizzled; r9-verified form) ----
    // tb2 stage: [fl 0..255][128 cols bf16] @0 (row 256B, 64KB)
    // h   stage: [fl 0..255][64 y bf16]     @65536 (row 128B, 32KB)
    float w1[16], b1[8], w2[8];
#pragma unroll
    for (int o = 0; o < 8; ++o) {
        w1[2 * o]     = c1w[2 * o];
        w1[2 * o + 1] = c1w[2 * o + 1];
        b1[o] = c1b[o];
        w2[o] = c2w[o];
    }
    const float b2v = c2b[0];
    const bool evenlane = ((lane & 1) == 0);

#pragma unroll
    for (int nt = 0; nt < 4; ++nt) {
        const int nl = wc * 64 + nt * 16 + lm;    // local col 0..127
        const int n = c0 + nl;
        const bool valid_c = (n < TCN);
        const float gv = valid_c ? gamma[permch(n)] : 0.0f;
        const int nbl = nl & ~1;
        const int yl  = nl >> 1;                  // 0..63
#pragma unroll
        for (int mt = 0; mt < 4; ++mt) {
#pragma unroll
            for (int rp = 0; rp < 2; ++rp) {
                const int ra = rp * 2;
                const int fl = wr * 64 + mt * 16 + lq * 4 + ra;   // 0..255
                const float ua = acc[mt][nt][ra] * gv;
                const float ub = acc[mt][nt][ra + 1] * gv;
                const float ta  = 2.0f / (1.0f + __expf(-2.0f * ua)) - 1.0f;
                const float tbv = 2.0f / (1.0f + __expf(-2.0f * ub)) - 1.0f;
                const float sa = __shfl_xor(ta, 1);
                const float sb = __shfl_xor(tbv, 1);
                const int  fme = evenlane ? fl : (fl + 1);
                const float re = evenlane ? ta : sb;
                const float im = evenlane ? sa : tbv;
                const unsigned pr2 = (unsigned)f2bf(re) |
                                     ((unsigned)f2bf(im) << 16);
                const int xr = ((fme & 1) << 5) | (((fme >> 2) & 1) << 6);
                *(unsigned*)(lds + fme * 256 + ((nbl * 2) ^ xr)) = pr2;
                float a2 = b2v;
#pragma unroll
                for (int o = 0; o < 8; ++o) {
                    const float a1 = fmaxf(
                        re * w1[2 * o] + im * w1[2 * o + 1] + b1[o], 0.0f);
                    a2 += a1 * w2[o];
                }
                const int xh = ((fme & 1) << 4) | (((fme >> 2) & 1) << 5);
                *(unsigned short*)(lds + 65536 + fme * 128 + ((yl * 2) ^ xh)) =
                    f2bf(fmaxf(a2, 0.0f));
            }
        }
    }
    __syncthreads();

    // ---- epilogue E2: coalesced copy-out (full-line stores) ----
    const int vch = min(16, max(0, (520 - (c0 >> 1)) >> 2));   // 16B tb2 chunks
#pragma unroll
    for (int i = 0; i < 8; ++i) {
        const int c = i * 512 + tid;              // chunk 0..4095
        const int fl = c >> 4;                    // row 0..255
        const int c16 = c & 15;
        const int fg = m0 + fl;
        if (fg < MROWS && c16 < vch) {
            const int b = fg / FN, f = fg - b * FN;
            const int xr = ((fl & 1) << 5) | (((fl >> 2) & 1) << 6);
            const intx4 v = *(const intx4*)(lds + fl * 256 + ((c16 * 16) ^ xr));
            *(intx4*)(tb2 + (size_t)b * FLATB + (size_t)f * TBP +
                      (c0 + c16 * 8)) = v;
        }
    }
    const int vhc = min(8, max(0, (544 - (c0 >> 1)) >> 3));    // 16B h chunks
#pragma unroll
    for (int i = 0; i < 4; ++i) {
        const int c = i * 512 + tid;              // chunk 0..2047
        const int fl = c >> 3;                    // row 0..255
        const int c16 = c & 7;
        const int fg = m0 + fl;
        if (fg < MROWS && c16 < vhc) {
            const int xh = ((fl & 1) << 4) | (((fl >> 2) & 1) << 5);
            const intx4 v = *(const intx4*)(lds + 65536 + fl * 128 +
                                            ((c16 * 16) ^ xh));
            *(intx4*)(h + (size_t)fg * KPH + ((c0 >> 1) + c16 * 8)) = v;
        }
    }
}

// ---------------------------------------------------------------------------
// k_maskm (MFMA): hh = H * Wlin^T; mask = sigmoid(2*(hh+b)*g);
// RMW: one aligned uint per (m,y) scales the (re,im) pair in tb2.
// (round-7 banked version)
// ---------------------------------------------------------------------------
__global__ __launch_bounds__(256) void k_maskm(
    const unsigned short* __restrict__ h, const unsigned short* __restrict__ wlb,
    const float* __restrict__ linb, const float* __restrict__ fcg,
    unsigned* __restrict__ tbu)
{
    __shared__ __align__(16) unsigned short As[128 * 32];
    __shared__ __align__(16) unsigned short Bs[128 * 32];

    const int m0 = blockIdx.x * 128, n0 = blockIdx.y * 128;
    const int tid = threadIdx.x;

    const int s0 = tid, s1 = tid + 256;
    const int ar0 = s0 >> 2, aq0 = s0 & 3;
    const int ar1 = s1 >> 2, aq1 = s1 & 3;
    const unsigned short* ga0 = h + (size_t)(m0 + ar0) * KPH + aq0 * 8;
    const unsigned short* ga1 = h + (size_t)(m0 + ar1) * KPH + aq1 * 8;
    const unsigned short* gb0 = wlb + (size_t)(n0 + ar0) * KPH + aq0 * 8;
    const unsigned short* gb1 = wlb + (size_t)(n0 + ar1) * KPH + aq1 * 8;
    unsigned short* la0 = &As[s0 * 8];
    unsigned short* la1 = &As[s1 * 8];
    unsigned short* lb0 = &Bs[s0 * 8];
    unsigned short* lb1 = &Bs[s1 * 8];

    const int wave = tid >> 6, lane = tid & 63;
    const int lm = lane & 15, lq = lane >> 4;
    const int mw = (wave & 1) * 64, nw = (wave >> 1) * 64;
    const unsigned short* Ap = &As[(mw + lm) * 32 + lq * 8];
    const unsigned short* Bp = &Bs[(nw + lm) * 32 + lq * 8];

    floatx4 acc[4][4];
#pragma unroll
    for (int i = 0; i < 4; ++i)
#pragma unroll
        for (int j = 0; j < 4; ++j) acc[i][j] = (floatx4)0.0f;

    for (int ks = 0; ks < KPH / 32; ++ks) {
        load_lds16(ga0, la0);
        load_lds16(ga1, la1);
        load_lds16(gb0, lb0);
        load_lds16(gb1, lb1);
        ga0 += 32; ga1 += 32; gb0 += 32; gb1 += 32;
        __syncthreads();

        bf16x8 afr[4], bfr[4];
#pragma unroll
        for (int mt = 0; mt < 4; ++mt) afr[mt] = *(const bf16x8*)(Ap + mt * 16 * 32);
#pragma unroll
        for (int nt = 0; nt < 4; ++nt) bfr[nt] = *(const bf16x8*)(Bp + nt * 16 * 32);
#pragma unroll
        for (int mt = 0; mt < 4; ++mt)
#pragma unroll
            for (int nt = 0; nt < 4; ++nt)
                acc[mt][nt] = __builtin_amdgcn_mfma_f32_16x16x32_bf16(
                    afr[mt], bfr[nt], acc[mt][nt], 0, 0, 0);
        __syncthreads();
    }

#pragma unroll
    for (int nt = 0; nt < 4; ++nt) {
        const int y = n0 + nw + nt * 16 + lm;
        if (y < CUTN) {
            const float lb = linb[y];
            const float gv = fcg[y];
#pragma unroll
            for (int mt = 0; mt < 4; ++mt) {
#pragma unroll
                for (int r = 0; r < 4; ++r) {
                    const int m = m0 + mw + mt * 16 + lq * 4 + r;
                    if (m < MROWS) {
                        const float v = (acc[mt][nt][r] + lb) * gv;
                        const float msk = 1.0f / (1.0f + __expf(-2.0f * v));
                        unsigned* p = tbu + (size_t)m * (TBP / 2) + y;
                        const unsigned u = *p;
                        const float re = bf2f((unsigned short)(u & 0xffffu)) * msk;
                        const float im = bf2f((unsigned short)(u >> 16)) * msk;
                        *p = (unsigned)f2bf(re) | ((unsigned)f2bf(im) << 16);
                    }
                }
            }
        }
    }
}

// ---------------------------------------------------------------------------
// k_convtm (MFMA): d[m][r] = A(tb2 windows) * Wd^T, fused sigmoid softmax.
// (round-7 banked version: 128x128, BK=64, T3-minimum dbuf, LDS-staged out)
// ---------------------------------------------------------------------------
__global__ __launch_bounds__(256) void k_convtm(
    const unsigned short* __restrict__ tb2, const unsigned short* __restrict__ wdb,
    float* __restrict__ out)
{
    extern __shared__ __align__(16) char lds[];   // 64KB (2x32KB dbuf; reused as stage)

    const int m0 = blockIdx.x * 128, n0 = blockIdx.y * 128;
    const int b   = m0 >> 10;
    const int ml0 = m0 & 1023;
    const int tid = threadIdx.x;

    const unsigned short* tbb = tb2 + (size_t)b * FLATB;
    const unsigned short* ga[4];
    const unsigned short* gb[4];
    int qa[4];
#pragma unroll
    for (int i = 0; i < 4; ++i) {
        const int c = i * 256 + tid;             // chunk 0..1023
        const int row = c >> 3;                  // 0..127
        const int colb = (c & 7) * 16;
        const int es = (colb ^ ((row & 7) << 4)) >> 1;
        qa[i] = c * 16;
        ga[i] = tbb + (size_t)(ml0 + row + 1) * TBP + es;
        gb[i] = wdb + (size_t)(n0 + row) * KPC + es;
    }

    const int wave = tid >> 6, lane = tid & 63;
    const int lm = lane & 15, lq = lane >> 4;
    const int mw = (wave & 1) * 64, nw = (wave >> 1) * 64;
    const int swz = (lm & 7) << 4;
    int abo[2], bbo[2];
#pragma unroll
    for (int ks = 0; ks < 2; ++ks) {
        abo[ks] = (mw + lm) * 128 + ((ks * 64 + lq * 16) ^ swz);
        bbo[ks] = 16384 + (nw + lm) * 128 + ((ks * 64 + lq * 16) ^ swz);
    }

    floatx4 acc[4][4];
#pragma unroll
    for (int i = 0; i < 4; ++i)
#pragma unroll
        for (int j = 0; j < 4; ++j) acc[i][j] = (floatx4)0.0f;

    // prologue: stage K-tile 0 into buf 0
#pragma unroll
    for (int i = 0; i < 4; ++i) {
        load_lds16(ga[i], lds + qa[i]);
        load_lds16(gb[i], lds + 16384 + qa[i]);
        ga[i] += 64; gb[i] += 64;
    }
    __syncthreads();

    for (int t = 0; t < KPC / 64; ++t) {
        char* cur = lds + (t & 1) * 32768;
        char* nxt = lds + ((t + 1) & 1) * 32768;

        if (t + 1 < KPC / 64) {
#pragma unroll
            for (int i = 0; i < 4; ++i) {
                load_lds16(ga[i], nxt + qa[i]);
                load_lds16(gb[i], nxt + 16384 + qa[i]);
                ga[i] += 64; gb[i] += 64;
            }
        }

        bf16x8 afr[4][2], bfr[4][2];
#pragma unroll
        for (int mt = 0; mt < 4; ++mt)
#pragma unroll
            for (int ks = 0; ks < 2; ++ks)
                afr[mt][ks] = *(const bf16x8*)(cur + abo[ks] + mt * 2048);
#pragma unroll
        for (int nt = 0; nt < 4; ++nt)
#pragma unroll
            for (int ks = 0; ks < 2; ++ks)
                bfr[nt][ks] = *(const bf16x8*)(cur + bbo[ks] + nt * 2048);
#pragma unroll
        for (int mt = 0; mt < 4; ++mt)
#pragma unroll
            for (int nt = 0; nt < 4; ++nt)
#pragma unroll
                for (int ks = 0; ks < 2; ++ks)
                    acc[mt][nt] = __builtin_amdgcn_mfma_f32_16x16x32_bf16(
                        afr[mt][ks], bfr[nt][ks], acc[mt][nt], 0, 0, 0);
        __syncthreads();
    }

    // ---- E1: stage p0 block into LDS: [ml 0..127][nl 0..127] f32 (64KB) ----
#pragma unroll
    for (int nt = 0; nt < 4; ++nt) {
        const int nl = nw + nt * 16 + lm;
#pragma unroll
        for (int mt = 0; mt < 4; ++mt) {
#pragma unroll
            for (int r = 0; r < 4; ++r) {
                const int ml = mw + mt * 16 + lq * 4 + r;
                const float d = acc[mt][nt][r];
                const float p0 = 1.0f / (1.0f + __expf(-d));
                *(float*)(lds + ml * 512 + nl * 4) = p0;
            }
        }
    }
    __syncthreads();

    // ---- E2: coalesced copy-out (full 128B lines), p and 1-p ----
    float* ob = out + (size_t)b * 2 * TIME_N;
#pragma unroll
    for (int i = 0; i < 16; ++i) {
        const int c = i * 256 + tid;             // chunk 0..4095 (16B)
        const int ml = c >> 5;                   // row 0..127
        const int c16 = c & 31;                  // chunk in row
        const floatx4 v = *(const floatx4*)(lds + c * 16);
        floatx4 w;
        w[0] = 1.0f - v[0]; w[1] = 1.0f - v[1];
        w[2] = 1.0f - v[2]; w[3] = 1.0f - v[3];
        const int tau = (ml0 + ml) * 256 + n0 + c16 * 4;
        *(floatx4*)(ob + tau)          = v;
        *(floatx4*)(ob + TIME_N + tau) = w;
    }
}

extern "C" void kernel_launch(void* const* d_in, const int* in_sizes, int n_in,
                              void* d_out, int out_size, void* d_ws, size_t ws_size,
                              hipStream_t stream)
{
    const float* x    = (const float*)d_in[0];
    const float* c1w  = (const float*)d_in[1];
    const float* ing  = (const float*)d_in[2];
    const float* cb1w = (const float*)d_in[3];
    const float* cb1b = (const float*)d_in[4];
    const float* cb2w = (const float*)d_in[5];
    const float* cb2b = (const float*)d_in[6];
    const float* linw = (const float*)d_in[7];
    const float* linb = (const float*)d_in[8];
    const float* fcg  = (const float*)d_in[9];
    const float* ctw  = (const float*)d_in[10];
    float* out = (float*)d_out;

    // ---- workspace layout (all bf16) ----
    unsigned short* tb2 = (unsigned short*)d_ws;           // 32*1029*1040
    unsigned short* h   = tb2 + (size_t)BATCH * FLATB;     // 33024*544
    unsigned short* wlb = h + (size_t)MP * KPH;            // 640*544
    unsigned short* xb  = wlb + (size_t)NPH * KPH;         // 32*XLEN
    unsigned short* wbf = xb + (size_t)BATCH * XLEN;       // 1152*1024
    unsigned short* wdb = wbf + (size_t)CPAD * KW;         // 256*4160

    hipLaunchKernelGGL(k_prep, dim3(PB_TOTAL), dim3(256), 0, stream,
                       x, c1w, linw, ctw, xb, wbf, wlb, wdb);
    hipLaunchKernelGGL(k_conv1m, dim3(C1_NWG), dim3(512), C1_LDS, stream,
                       xb, wbf, ing, cb1w, cb1b, cb2w, cb2b, tb2, h);
    hipLaunchKernelGGL(k_maskm, dim3(MP / 128, NPH / 128), dim3(256), 0, stream,
                       h, wlb, linb, fcg, (unsigned*)tb2);
    hipLaunchKernelGGL(k_convtm, dim3(256, 2), dim3(256), 65536, stream,
                       tb2, wdb, out);
}